// Round 8
// baseline (69.719 us; speedup 1.0000x reference)
//
#include <hip/hip_runtime.h>

#define S_DIM 363      // GRID = ceil(sqrt(2)*256)
#define S_P   368      // per-angle row stride in 8-B entries (16-B multiple)
#define A_DIM 180      // N_THETA
#define OUT_W 256
#define F_PI 3.14159265358979323846f
#define W_C  (-2.0f / (F_PI * F_PI))   // conv weight scale: w(d) = W_C / d^2

typedef float    f4 __attribute__((ext_vector_type(4)));
typedef _Float16 h4 __attribute__((ext_vector_type(4)));
union HU { uint2 u; h4 h; };

// Filtered sinogram, plain fp16 layout: g_sino[a*S_P + 1 + t] = y_a[t] for all
// 4 batches (8 B, batch-interleaved). Guards g[a][0] = g[a][364] = 0 reproduce
// the reference's clip+zero-weight edge semantics exactly (k1 = floor(pos)+1
// in [0,363]; lo = entry k1 = y[k1-1] or guard, hi = entry k1+1 = y[k1] or
// guard). Fully rewritten every launch before kernel 2 reads it; the kernel
// boundary is the grid barrier (R4/R5: software grid barriers cost ~30-70 us
// on this 8-XCD chip vs ~3 us for the dispatch boundary -- fusion dead end).
__device__ uint2  g_sino[A_DIM * S_P];
// (cos, sin) per angle, computed ONCE by kernel 1 (one thread per block).
__device__ float2 g_csn[A_DIM];

// ---------------------------------------------------------------------------
// Kernel 1 (unchanged from R7 -- split-sum delivered its predicted -3 us):
// ramp filter as direct spatial conv (exact rewrite of the reference FFT
// path: circular conv, g[0]=0.5, g[d]=-2/(pi*d)^2 odd d, 0 even d).
// 768 threads / 12 waves: output t's ~181 odd taps split by (s-t) mod 4 into
// two ~91-tap step-4 progressions (thread u and u+363); halves merged via LDS
// with the 0.5*x[t] term. Weights via v_rcp_f32 (~1e-7 rel err, invisible
// under fp16 storage). Uniform trip count, conflict-free LDS.
// ---------------------------------------------------------------------------
__global__ __launch_bounds__(768) void iradon_filter_kernel(
        const float* __restrict__ x) {
    __shared__ f4 xs4[S_DIM];      // per-s, batch-interleaved f32
    __shared__ f4 red[726];        // half-sums: [0,363) = h0, [363,726) = h1

    const int a   = blockIdx.x;    // 0..179
    const int tid = threadIdx.x;   // 0..767

    // ---- stage: 1452 scalars (4 batches x 363 s), 2 per thread, scattered
    {
        float* lds = (float*)xs4;  // element (s, b) at index s*4 + b
        int n = tid;               // n = b*363 + s
        #pragma unroll 2
        for (int r = 0; r < 2; ++r, n += 768) {
            if (n < 4 * S_DIM) {
                int b = (n >= 3 * S_DIM) ? 3 : (n >= 2 * S_DIM) ? 2
                      : (n >= S_DIM) ? 1 : 0;
                int s = n - b * S_DIM;
                lds[s * 4 + b] = x[n * A_DIM + a];   // x[(b*363+s)*180 + a]
            }
        }
    }
    if (tid == 728) {              // this block's angle -> trig table (once)
        float th = (float)a * (F_PI / 180.0f);
        g_csn[a] = make_float2(cosf(th), sinf(th));
    }
    __syncthreads();

    // ---- split-sum conv: thread u handles output t = u % 363, half u / 363
    if (tid < 726) {
        const int t  = (tid >= S_DIM) ? tid - S_DIM : tid;
        const int p0 = (tid >= S_DIM) ? ((t + 3) & 3) : ((t + 1) & 3);
        f4 acc = (f4)0.0f;
        float df = (float)(p0 - t);          // d = s - t, steps by 4
        #pragma unroll 4
        for (int s = p0; s < S_DIM; s += 4, df += 4.0f) {
            f4 v = xs4[s];                   // 4 phase-addrs/wave, conflict-free
            float w = W_C * __builtin_amdgcn_rcpf(df * df);
            acc += w * v;                    // 2x v_pk_fma_f32
        }
        red[tid] = acc;
    }
    __syncthreads();

    // ---- merge halves + d==0 term, convert to fp16, store
    if (tid < S_DIM) {
        f4 tot = 0.5f * xs4[tid] + red[tid] + red[tid + S_DIM];
        HU r; r.h = __builtin_convertvector(tot, h4);
        g_sino[a * S_P + 1 + tid] = r.u;
    }
    if (tid == 726) { HU z; z.u.x = 0u; z.u.y = 0u; g_sino[a * S_P + 0]   = z.u; }
    if (tid == 727) { HU z; z.u.x = 0u; z.u.y = 0u; g_sino[a * S_P + 364] = z.u; }
}

// ---------------------------------------------------------------------------
// Kernel 2: backprojection. R8 change -- same medicine K1 got in R7: the
// 45-iter angle loop is the per-wave critical path (per-iter chain: LDS cn ->
// 2 fma -> floor/cvt -> addr -> ~200-300cy L2 load -> 8 fma_mix; VGPR=36
// shows no deep compiler pipeline; VALUBusy ~12% says latency-bound).
// Split angles 8 ways: block = 512 thr (8 waves), wave q owns angles
// [(q*45)>>1, ((q+1)*45)>>1) -- 22/23 iters, HALF the serial path -- and the
// grid's 1024 blocks now give 32 waves/CU (max occupancy, was 16), doubling
// latency-hiding TLP. Reduction merges 8 partials (one extra LDS pass).
// pos = (j-128)*cos - (i-128)*sin + 181; k1 = floor(pos)+1 in [0,363];
// lo = g[a][k1], hi = g[a][k1+1] (adjacent 8-B loads, second folds to
// offset:8); f32 accum via v_fma_mix. Trig from g_csn (coalesced, L2-hit).
// ---------------------------------------------------------------------------
__global__ __launch_bounds__(512) void iradon_backproject_kernel(
        float* __restrict__ out) {
    __shared__ float2 csn[A_DIM];
    __shared__ f4 red[512];

    const int tid = threadIdx.x;
    if (tid < A_DIM) csn[tid] = g_csn[tid];   // coalesced 8B loads, L2-hit
    __syncthreads();

    const int px = tid & 63;
    const int q  = tid >> 6;           // wave index = angle eighth (uniform/wave)
    const int j  = blockIdx.x * 64 + px;
    const int i  = blockIdx.y;

    const float jj  = (float)(j - 128);
    const float nii = (float)(128 - i);    // -(i-128), wave-uniform

    f4 acc = (f4)0.0f;
    const int a0   = (q * 45) >> 1;        // 0,22,45,67,90,112,135,157
    const int aend = ((q + 1) * 45) >> 1;  // 22,45,67,90,112,135,157,180
    #pragma unroll 2
    for (int a = a0; a < aend; ++a) {
        const float2 cn = csn[a];          // one ds_read_b64 broadcast
        float pos = fmaf(jj, cn.x, fmaf(nii, cn.y, 181.0f));
        float f   = floorf(pos);
        int   k1  = (int)f + 1;            // in [0, 363]
        float w1  = pos - f;
        float w0  = 1.0f - w1;
        const uint2* __restrict__ row = g_sino + a * S_P;
        HU lo, hi;
        lo.u = row[k1];                    // y[k]   x4 batches (8 B)
        hi.u = row[k1 + 1];                // y[k+1] x4 batches (offset:8)
        acc.x = fmaf((float)lo.h.x, w0, fmaf((float)hi.h.x, w1, acc.x));
        acc.y = fmaf((float)lo.h.y, w0, fmaf((float)hi.h.y, w1, acc.y));
        acc.z = fmaf((float)lo.h.z, w0, fmaf((float)hi.h.z, w1, acc.z));
        acc.w = fmaf((float)lo.h.w, w0, fmaf((float)hi.h.w, w1, acc.w));
    }

    red[tid] = acc;
    __syncthreads();

    if (tid < 64) {
        f4 r = red[tid];
        #pragma unroll 7
        for (int k = 1; k < 8; ++k) r += red[tid + 64 * k];
        r *= (F_PI / 360.0f);
        const int jo   = blockIdx.x * 64 + tid;
        const size_t p = (size_t)blockIdx.y * OUT_W + jo;
        out[p]              = r.x;
        out[p +     65536]  = r.y;
        out[p + 2 * 65536]  = r.z;
        out[p + 3 * 65536]  = r.w;
    }
}

extern "C" void kernel_launch(void* const* d_in, const int* in_sizes, int n_in,
                              void* d_out, int out_size, void* d_ws, size_t ws_size,
                              hipStream_t stream) {
    const float* x = (const float*)d_in[0];
    float* out = (float*)d_out;

    iradon_filter_kernel<<<dim3(A_DIM), 768, 0, stream>>>(x);
    iradon_backproject_kernel<<<dim3(4, OUT_W), 512, 0, stream>>>(out);
}

// Round 9
// 68.446 us; speedup vs baseline: 1.0186x; 1.0186x over previous
//
#include <hip/hip_runtime.h>

#define S_DIM 363      // GRID = ceil(sqrt(2)*256)
#define S_P   368      // per-angle row stride in 8-B entries (16-B multiple)
#define A_DIM 180      // N_THETA
#define OUT_W 256
#define F_PI 3.14159265358979323846f
#define W_C  (-2.0f / (F_PI * F_PI))   // conv weight scale: w(d) = W_C / d^2

typedef float    f4 __attribute__((ext_vector_type(4)));
typedef _Float16 h4 __attribute__((ext_vector_type(4)));
union HU { uint2 u; h4 h; };

// Filtered sinogram, plain fp16 layout: g_sino[a*S_P + 1 + t] = y_a[t] for all
// 4 batches (8 B, batch-interleaved). Guards g[a][0] = g[a][364] = 0 reproduce
// the reference's clip+zero-weight edge semantics exactly (k1 = floor(pos)+1
// in [0,363]; lo = entry k1 = y[k1-1] or guard, hi = entry k1+1 = y[k1] or
// guard). Fully rewritten every launch before kernel 2 reads it; the kernel
// boundary is the grid barrier (R4/R5: software grid barriers cost ~30-70 us
// on this 8-XCD chip vs ~3 us for the dispatch boundary -- fusion dead end).
__device__ uint2  g_sino[A_DIM * S_P];
// (cos, sin) per angle, computed ONCE by kernel 1 (one thread per block).
__device__ float2 g_csn[A_DIM];

// ---------------------------------------------------------------------------
// Kernel 1 (unchanged from R7 -- split-sum delivered its predicted -3 us):
// ramp filter as direct spatial conv (exact rewrite of the reference FFT
// path: circular conv, g[0]=0.5, g[d]=-2/(pi*d)^2 odd d, 0 even d).
// 768 threads / 12 waves: output t's ~181 odd taps split by (s-t) mod 4 into
// two ~91-tap step-4 progressions (thread u and u+363); halves merged via LDS
// with the 0.5*x[t] term. Weights via v_rcp_f32 (~1e-7 rel err, invisible
// under fp16 storage). Uniform trip count, conflict-free LDS.
// ---------------------------------------------------------------------------
__global__ __launch_bounds__(768) void iradon_filter_kernel(
        const float* __restrict__ x) {
    __shared__ f4 xs4[S_DIM];      // per-s, batch-interleaved f32
    __shared__ f4 red[726];        // half-sums: [0,363) = h0, [363,726) = h1

    const int a   = blockIdx.x;    // 0..179
    const int tid = threadIdx.x;   // 0..767

    // ---- stage: 1452 scalars (4 batches x 363 s), 2 per thread, scattered
    {
        float* lds = (float*)xs4;  // element (s, b) at index s*4 + b
        int n = tid;               // n = b*363 + s
        #pragma unroll 2
        for (int r = 0; r < 2; ++r, n += 768) {
            if (n < 4 * S_DIM) {
                int b = (n >= 3 * S_DIM) ? 3 : (n >= 2 * S_DIM) ? 2
                      : (n >= S_DIM) ? 1 : 0;
                int s = n - b * S_DIM;
                lds[s * 4 + b] = x[n * A_DIM + a];   // x[(b*363+s)*180 + a]
            }
        }
    }
    if (tid == 728) {              // this block's angle -> trig table (once)
        float th = (float)a * (F_PI / 180.0f);
        g_csn[a] = make_float2(cosf(th), sinf(th));
    }
    __syncthreads();

    // ---- split-sum conv: thread u handles output t = u % 363, half u / 363
    if (tid < 726) {
        const int t  = (tid >= S_DIM) ? tid - S_DIM : tid;
        const int p0 = (tid >= S_DIM) ? ((t + 3) & 3) : ((t + 1) & 3);
        f4 acc = (f4)0.0f;
        float df = (float)(p0 - t);          // d = s - t, steps by 4
        #pragma unroll 4
        for (int s = p0; s < S_DIM; s += 4, df += 4.0f) {
            f4 v = xs4[s];                   // 4 phase-addrs/wave, conflict-free
            float w = W_C * __builtin_amdgcn_rcpf(df * df);
            acc += w * v;                    // 2x v_pk_fma_f32
        }
        red[tid] = acc;
    }
    __syncthreads();

    // ---- merge halves + d==0 term, convert to fp16, store
    if (tid < S_DIM) {
        f4 tot = 0.5f * xs4[tid] + red[tid] + red[tid + S_DIM];
        HU r; r.h = __builtin_convertvector(tot, h4);
        g_sino[a * S_P + 1 + tid] = r.u;
    }
    if (tid == 726) { HU z; z.u.x = 0u; z.u.y = 0u; g_sino[a * S_P + 0]   = z.u; }
    if (tid == 727) { HU z; z.u.x = 0u; z.u.y = 0u; g_sino[a * S_P + 364] = z.u; }
}

// ---------------------------------------------------------------------------
// Kernel 2: backprojection -- REVERTED to the proven R7 structure (R8's
// 8-way split regressed +1.0 us: its runtime loop bounds + unroll 2 cut the
// per-wave in-flight loads from ~10 to ~4; unroll depth over a CONSTANT trip
// count IS the memory-level parallelism here). One change vs R7: unroll
// 5 -> 9 (45 = 9*5), doubling load-overlap depth along the validated axis.
// ~6 VGPR/in-flight iter x 9 + ~20 base ≈ 74 < 128 cap at 4 waves/SIMD.
// pos = (j-128)*cos - (i-128)*sin + 181; f = floor(pos), k1 = (int)f + 1 in
// [0,363]: lo = g[a][k1], hi = g[a][k1+1] -- two adjacent 8-B loads, second
// folds to offset:8; f32 accum via v_fma_mix (chain order identical to R7 ->
// absmax bit-identical). Trig from g_csn (coalesced, L2-hit). Block =
// 256 thr = 64(j) x 4 angle-quarters, one output row per block; partials
// merged through LDS. Grid = 4 x 256 (1024 blocks, 4/CU, 16 waves/CU).
// ---------------------------------------------------------------------------
__global__ __launch_bounds__(256) void iradon_backproject_kernel(
        float* __restrict__ out) {
    __shared__ float2 csn[A_DIM];
    __shared__ f4 red[256];

    const int tid = threadIdx.x;
    if (tid < A_DIM) csn[tid] = g_csn[tid];   // coalesced 8B loads, L2-hit
    __syncthreads();

    const int px = tid & 63;
    const int q  = tid >> 6;           // wave index = angle quarter (uniform/wave)
    const int j  = blockIdx.x * 64 + px;
    const int i  = blockIdx.y;

    const float jj  = (float)(j - 128);
    const float nii = (float)(128 - i);    // -(i-128), wave-uniform

    f4 acc = (f4)0.0f;
    const int a0 = q * 45;
    #pragma unroll 9
    for (int m = 0; m < 45; ++m) {
        const int a = a0 + m;
        const float2 cn = csn[a];          // one ds_read_b64 broadcast
        float pos = fmaf(jj, cn.x, fmaf(nii, cn.y, 181.0f));
        float f   = floorf(pos);
        int   k1  = (int)f + 1;            // in [0, 363]
        float w1  = pos - f;
        float w0  = 1.0f - w1;
        const uint2* __restrict__ row = g_sino + a * S_P;
        HU lo, hi;
        lo.u = row[k1];                    // y[k]   x4 batches (8 B)
        hi.u = row[k1 + 1];                // y[k+1] x4 batches (offset:8)
        acc.x = fmaf((float)lo.h.x, w0, fmaf((float)hi.h.x, w1, acc.x));
        acc.y = fmaf((float)lo.h.y, w0, fmaf((float)hi.h.y, w1, acc.y));
        acc.z = fmaf((float)lo.h.z, w0, fmaf((float)hi.h.z, w1, acc.z));
        acc.w = fmaf((float)lo.h.w, w0, fmaf((float)hi.h.w, w1, acc.w));
    }

    red[tid] = acc;
    __syncthreads();

    if (tid < 64) {
        f4 r = red[tid] + red[tid + 64] + red[tid + 128] + red[tid + 192];
        r *= (F_PI / 360.0f);
        const int jo   = blockIdx.x * 64 + tid;
        const size_t p = (size_t)blockIdx.y * OUT_W + jo;
        out[p]              = r.x;
        out[p +     65536]  = r.y;
        out[p + 2 * 65536]  = r.z;
        out[p + 3 * 65536]  = r.w;
    }
}

extern "C" void kernel_launch(void* const* d_in, const int* in_sizes, int n_in,
                              void* d_out, int out_size, void* d_ws, size_t ws_size,
                              hipStream_t stream) {
    const float* x = (const float*)d_in[0];
    float* out = (float*)d_out;

    iradon_filter_kernel<<<dim3(A_DIM), 768, 0, stream>>>(x);
    iradon_backproject_kernel<<<dim3(4, OUT_W), 256, 0, stream>>>(out);
}